// Round 8
// baseline (385.221 us; speedup 1.0000x reference)
//
#include <hip/hip_runtime.h>
#include <stdint.h>
#include <stddef.h>

#define NB 2
#define NT 4096
#define NC 768
#define NH 12
#define ND 64

typedef unsigned short u16;
typedef __attribute__((ext_vector_type(4))) float f32x4;
typedef __attribute__((ext_vector_type(8))) unsigned short u16x8;
typedef __attribute__((ext_vector_type(4))) unsigned short u16x4;
typedef __attribute__((ext_vector_type(8))) __bf16 bf16x8;

__device__ __forceinline__ u16 f2bf(float f) {
  uint32_t u = __builtin_bit_cast(uint32_t, f);
  u += 0x7FFFu + ((u >> 16) & 1u);   // RTNE
  return (u16)(u >> 16);
}
__device__ __forceinline__ bf16x8 asbf(u16x8 v) { return __builtin_bit_cast(bf16x8, v); }

// pack two f32 -> two bf16, round-half-up: 3 VALU
__device__ __forceinline__ uint32_t pkbf(float a, float b) {
  uint32_t ua = __builtin_bit_cast(uint32_t, a) + 0x8000u;
  uint32_t ub = __builtin_bit_cast(uint32_t, b) + 0x8000u;
  return __builtin_amdgcn_perm(ub, ua, 0x07060302u);
}
// truncating pack (P only; numerator/denominator stay consistent): 1 VALU
__device__ __forceinline__ uint32_t pktr(float a, float b) {
  return __builtin_amdgcn_perm(__builtin_bit_cast(uint32_t, b),
                               __builtin_bit_cast(uint32_t, a), 0x07060302u);
}

// ---------------- cast fp32 -> bf16 ----------------
__global__ void k_cast(const float* __restrict__ in, u16* __restrict__ out, int n4) {
  int i = blockIdx.x * blockDim.x + threadIdx.x;
  if (i < n4) {
    f32x4 v = ((const f32x4*)in)[i];
    u16x4 o;
    o[0] = f2bf(v[0]); o[1] = f2bf(v[1]); o[2] = f2bf(v[2]); o[3] = f2bf(v[3]);
    ((u16x4*)out)[i] = o;
  }
}

// -------- transpose + cast --------
__global__ void k_transpose(const float* __restrict__ in, u16* __restrict__ out,
                            int R, int Cn) {
  __shared__ float tile[32][33];
  int c0 = blockIdx.x * 32, r0 = blockIdx.y * 32;
  int tx = threadIdx.x & 31, ty = threadIdx.x >> 5;
  for (int i = ty; i < 32; i += 8)
    tile[i][tx] = in[(size_t)(r0 + i) * Cn + c0 + tx];
  __syncthreads();
  for (int i = ty; i < 32; i += 8)
    out[(size_t)(c0 + i) * R + r0 + tx] = f2bf(tile[tx][i]);
}

// -------- GEMM: C[M,N] = A[M,K] * Bt[N,K]^T --------
// Pipelined: global loads for tile k0+32 issue right after the publish
// barrier of tile k0, overlapping the MFMA block (prefetch distance = one
// full compute phase). Padded LDS stride 40 (2-way conflicts only).
template <int EPI>
__global__ __launch_bounds__(256, 3)
void k_gemm_bt(const u16* __restrict__ A, const u16* __restrict__ Bt,
               int M, int N, int K,
               u16* __restrict__ o0, u16* __restrict__ o1, u16* __restrict__ o2,
               float* __restrict__ of) {
  __shared__ u16 As[128 * 40];
  __shared__ u16 Bs[128 * 40];
  const int tid = threadIdx.x;
  const int wave = tid >> 6, lane = tid & 63, quad = lane >> 4, lc = lane & 15;
  const int wm = (wave & 1) * 64, wn = (wave >> 1) * 64;
  const int bm = blockIdx.y * 128, bn = blockIdx.x * 128;

  const int sr = tid >> 2;
  const int sc8 = (tid & 3) * 8;
  const u16* ap0 = A + (size_t)(bm + sr) * K + sc8;
  const u16* ap1 = A + (size_t)(bm + 64 + sr) * K + sc8;
  const u16* bp0 = Bt + (size_t)(bn + sr) * K + sc8;
  const u16* bp1 = Bt + (size_t)(bn + 64 + sr) * K + sc8;
  u16* asl0 = &As[sr * 40 + sc8];
  u16* asl1 = &As[(64 + sr) * 40 + sc8];
  u16* bsl0 = &Bs[sr * 40 + sc8];
  u16* bsl1 = &Bs[(64 + sr) * 40 + sc8];

  f32x4 zv = {0.f, 0.f, 0.f, 0.f};
  f32x4 acc[4][4];
#pragma unroll
  for (int i = 0; i < 4; ++i)
#pragma unroll
    for (int j = 0; j < 4; ++j) acc[i][j] = zv;

  // preload k = 0
  u16x8 a0 = *(const u16x8*)(ap0);
  u16x8 a1 = *(const u16x8*)(ap1);
  u16x8 b0 = *(const u16x8*)(bp0);
  u16x8 b1 = *(const u16x8*)(bp1);

  for (int k0 = 0; k0 < K; k0 += 32) {
    __syncthreads();
    *(u16x8*)asl0 = a0;
    *(u16x8*)asl1 = a1;
    *(u16x8*)bsl0 = b0;
    *(u16x8*)bsl1 = b1;
    __syncthreads();
    if (k0 + 32 < K) {               // prefetch next tile over the MFMAs
      a0 = *(const u16x8*)(ap0 + k0 + 32);
      a1 = *(const u16x8*)(ap1 + k0 + 32);
      b0 = *(const u16x8*)(bp0 + k0 + 32);
      b1 = *(const u16x8*)(bp1 + k0 + 32);
    }

    bf16x8 af[4], bfv[4];
#pragma unroll
    for (int mi = 0; mi < 4; ++mi)
      af[mi] = asbf(*(const u16x8*)&As[(wm + mi * 16 + lc) * 40 + quad * 8]);
#pragma unroll
    for (int ni = 0; ni < 4; ++ni)
      bfv[ni] = asbf(*(const u16x8*)&Bs[(wn + ni * 16 + lc) * 40 + quad * 8]);
#pragma unroll
    for (int mi = 0; mi < 4; ++mi)
#pragma unroll
      for (int ni = 0; ni < 4; ++ni)
        acc[mi][ni] = __builtin_amdgcn_mfma_f32_16x16x32_bf16(af[mi], bfv[ni],
                                                              acc[mi][ni], 0, 0, 0);
  }

  const int mrow0 = bm + wm + quad * 4;
#pragma unroll
  for (int mi = 0; mi < 4; ++mi) {
    const int mbase = mrow0 + mi * 16;
#pragma unroll
    for (int ni = 0; ni < 4; ++ni) {
      const int n = bn + wn + ni * 16 + lc;
      if (EPI == 0) {
#pragma unroll
        for (int r = 0; r < 4; ++r)
          of[(size_t)(mbase + r) * N + n] = acc[mi][ni][r];
      } else {
        const int sect = n / NC;          // 0=q 1=k 2=v
        const int wn2 = n - sect * NC;
        const int h = wn2 >> 6, d = wn2 & 63;
        const int b = mbase >> 12;
        const int t = mbase & (NT - 1);
        const float sc = (sect == 0) ? 0.18033688011112042f : 1.0f;  // log2e/8
        if (sect == 2) {
          u16x4 pk;
#pragma unroll
          for (int r = 0; r < 4; ++r) pk[r] = f2bf(acc[mi][ni][r]);
          *(u16x4*)&o2[((size_t)(b * NH + h) * ND + d) * NT + t] = pk;
        } else {
          u16* dst = (sect == 0) ? o0 : o1;
#pragma unroll
          for (int r = 0; r < 4; ++r)
            dst[((size_t)(b * NH + h) * NT + (t + r)) * ND + d] =
                f2bf(acc[mi][ni][r] * sc);
        }
      }
    }
  }
}

// -------- flash attention, causal, transposed, MERGED dual Q-tiles --------
// Round-6 structure (register prefetch one tile ahead, lockstep KV walk,
// ones-row computes l via MFMA, no partials) with 4 blocks/CU residency.
#define LSK 72   // Ks/Vs stride (64 + pad 8)
__global__ __launch_bounds__(256, 4)
void k_attn(const u16* __restrict__ Q, const u16* __restrict__ K,
            const u16* __restrict__ Vt, u16* __restrict__ Y) {
  __shared__ u16 Ks[64 * LSK];        // [t][d]
  __shared__ u16 Vs[80 * LSK];        // [d][t]; rows 64..79 static ones/zeros
  __shared__ u16 Ps[4 * 2 * 16 * LSK];// per-wave, per-phase P^T as [q][t]

  const int tid = threadIdx.x;
  const int wave = tid >> 6, lane = tid & 63, quad = lane >> 4, lc = lane & 15;
  const int bh = blockIdx.x >> 5, pair = blockIdx.x & 31;
  const int b = bh / NH, h = bh - b * NH;
  const u16* Qb = Q + (size_t)bh * NT * ND;
  const u16* Kb = K + (size_t)bh * NT * ND;
  const u16* Vb = Vt + (size_t)bh * ND * NT;

  // static Vs rows: row 64 = 1.0 (bf16), rows 65..79 = 0
  for (int idx = tid; idx < 16 * 64; idx += 256) {
    int r = idx >> 6, c = idx & 63;
    Vs[(64 + r) * LSK + c] = (r == 0) ? (u16)0x3F80 : (u16)0;
  }

  const int qwA = pair * 64 + wave * 16;
  const int qwB = (63 - pair) * 64 + wave * 16;
  u16* PsA = &Ps[(wave * 2 + 0) * 16 * LSK];
  u16* PsB = &Ps[(wave * 2 + 1) * 16 * LSK];

  // Q as B-operand fragments (scale log2(e)/8 pre-folded into Q)
  bf16x8 bqA[2], bqB[2];
#pragma unroll
  for (int ks = 0; ks < 2; ++ks) {
    bqA[ks] = asbf(*(const u16x8*)(Qb + (size_t)(qwA + lc) * ND + ks * 32 + quad * 8));
    bqB[ks] = asbf(*(const u16x8*)(Qb + (size_t)(qwB + lc) * ND + ks * 32 + quad * 8));
  }

  f32x4 zv = {0.f, 0.f, 0.f, 0.f};
  f32x4 oA[5], oB[5];                 // O^T [dtile 0..3], [4] = l row
#pragma unroll
  for (int dt = 0; dt < 5; ++dt) { oA[dt] = zv; oB[dt] = zv; }

  const int kr = tid >> 3, kc = (tid & 7) * 8;   // staging: 32 rows x 64 cols
  const int ntiles = 64 - pair;

  // prefetch tile 0
  u16x8 kv0 = *(const u16x8*)(Kb + (size_t)kr * ND + kc);
  u16x8 kv1 = *(const u16x8*)(Kb + (size_t)(32 + kr) * ND + kc);
  u16x8 vv0 = *(const u16x8*)(Vb + (size_t)kr * NT + kc);
  u16x8 vv1 = *(const u16x8*)(Vb + (size_t)(32 + kr) * NT + kc);

#pragma unroll 1
  for (int tau = 0; tau < ntiles; ++tau) {
    const int t0 = tau * 64;
    __syncthreads();
    *(u16x8*)&Ks[kr * LSK + kc] = kv0;
    *(u16x8*)&Ks[(32 + kr) * LSK + kc] = kv1;
    *(u16x8*)&Vs[kr * LSK + kc] = vv0;
    *(u16x8*)&Vs[(32 + kr) * LSK + kc] = vv1;
    __syncthreads();
    if (tau + 1 < ntiles) {
      const int tn = t0 + 64;
      kv0 = *(const u16x8*)(Kb + (size_t)(tn + kr) * ND + kc);
      kv1 = *(const u16x8*)(Kb + (size_t)(tn + 32 + kr) * ND + kc);
      vv0 = *(const u16x8*)(Vb + (size_t)kr * NT + tn + kc);
      vv1 = *(const u16x8*)(Vb + (size_t)(32 + kr) * NT + tn + kc);
    }

    const bool actA = (tau <= pair);   // block-uniform

    // S^T = K Q^T for both phases, sharing K fragments
    f32x4 sA[4], sB[4];
#pragma unroll
    for (int mt = 0; mt < 4; ++mt) { sA[mt] = zv; sB[mt] = zv; }
#pragma unroll
    for (int ks = 0; ks < 2; ++ks) {
      bf16x8 ak[4];
#pragma unroll
      for (int mt = 0; mt < 4; ++mt)
        ak[mt] = asbf(*(const u16x8*)&Ks[(mt * 16 + lc) * LSK + ks * 32 + quad * 8]);
      if (actA) {
#pragma unroll
        for (int mt = 0; mt < 4; ++mt)
          sA[mt] = __builtin_amdgcn_mfma_f32_16x16x32_bf16(ak[mt], bqA[ks], sA[mt], 0, 0, 0);
      }
#pragma unroll
      for (int mt = 0; mt < 4; ++mt)
        sB[mt] = __builtin_amdgcn_mfma_f32_16x16x32_bf16(ak[mt], bqB[ks], sB[mt], 0, 0, 0);
    }

    // exp2 + truncating pack -> Ps (P^T rows = q = lc)
    if (actA) {
      const bool mskA = (tau == pair);
#pragma unroll
      for (int mt = 0; mt < 4; ++mt) {
        float e[4];
#pragma unroll
        for (int r = 0; r < 4; ++r) {
          float v = sA[mt][r];
          if (mskA) {
            int tg = t0 + mt * 16 + quad * 4 + r;
            v = (tg > qwA + lc) ? -1e30f : v;
          }
          e[r] = exp2f(v);
        }
        uint2 w;
        w.x = pktr(e[0], e[1]);
        w.y = pktr(e[2], e[3]);
        *(uint2*)&PsA[lc * LSK + mt * 16 + quad * 4] = w;
      }
    }
    {
      const bool mskB = (tau == ntiles - 1);
#pragma unroll
      for (int mt = 0; mt < 4; ++mt) {
        float e[4];
#pragma unroll
        for (int r = 0; r < 4; ++r) {
          float v = sB[mt][r];
          if (mskB) {
            int tg = t0 + mt * 16 + quad * 4 + r;
            v = (tg > qwB + lc) ? -1e30f : v;
          }
          e[r] = exp2f(v);
        }
        uint2 w;
        w.x = pktr(e[0], e[1]);
        w.y = pktr(e[2], e[3]);
        *(uint2*)&PsB[lc * LSK + mt * 16 + quad * 4] = w;
      }
    }

    // O^T += V^T P^T for both phases, sharing V fragments
#pragma unroll
    for (int ks = 0; ks < 2; ++ks) {
      bf16x8 av[5];
#pragma unroll
      for (int dt = 0; dt < 5; ++dt)
        av[dt] = asbf(*(const u16x8*)&Vs[(dt * 16 + lc) * LSK + ks * 32 + quad * 8]);
      if (actA) {
        bf16x8 bp = asbf(*(const u16x8*)&PsA[lc * LSK + ks * 32 + quad * 8]);
#pragma unroll
        for (int dt = 0; dt < 5; ++dt)
          oA[dt] = __builtin_amdgcn_mfma_f32_16x16x32_bf16(av[dt], bp, oA[dt], 0, 0, 0);
      }
      {
        bf16x8 bp = asbf(*(const u16x8*)&PsB[lc * LSK + ks * 32 + quad * 8]);
#pragma unroll
        for (int dt = 0; dt < 5; ++dt)
          oB[dt] = __builtin_amdgcn_mfma_f32_16x16x32_bf16(av[dt], bp, oB[dt], 0, 0, 0);
      }
    }
  }

  // epilogue: l = row 64 of O^T (lane lc, quad 0, reg 0); normalize, write Y
#pragma unroll
  for (int phx = 0; phx < 2; ++phx) {
    const f32x4* o = phx ? oB : oA;
    const int qg = (phx ? qwB : qwA) + lc;
    float l = __shfl(o[4][0], lc);
    float inv = 1.f / l;
    u16* yrow = Y + (size_t)(b * NT + qg) * NC + h * 64;
#pragma unroll
    for (int dt = 0; dt < 4; ++dt) {
      uint2 w;
      w.x = pkbf(o[dt][0] * inv, o[dt][1] * inv);
      w.y = pkbf(o[dt][2] * inv, o[dt][3] * inv);
      *(uint2*)&yrow[dt * 16 + quad * 4] = w;
    }
  }
}

extern "C" void kernel_launch(void* const* d_in, const int* in_sizes, int n_in,
                              void* d_out, int out_size, void* d_ws, size_t ws_size,
                              hipStream_t stream) {
  (void)in_sizes; (void)n_in; (void)out_size; (void)ws_size;
  const float* x = (const float*)d_in[0];
  const float* w_qkv = (const float*)d_in[1];
  const float* w_out = (const float*)d_in[2];
  float* out = (float*)d_out;

  u16* ws = (u16*)d_ws;
  const size_t XE = (size_t)NB * NT * NC;       // 6291456 elements
  u16* xb  = ws;
  u16* wqT = xb + XE;
  u16* woT = wqT + (size_t)3 * NC * NC;
  u16* Qb  = woT + (size_t)NC * NC;
  u16* Kb  = Qb + XE;
  u16* Vtb = Kb + XE;
  u16* yb  = Vtb + XE;

  k_cast<<<(int)(XE / 4 / 256), 256, 0, stream>>>(x, xb, (int)(XE / 4));
  k_transpose<<<dim3(3 * NC / 32, NC / 32), 256, 0, stream>>>(w_qkv, wqT, NC, 3 * NC);
  k_transpose<<<dim3(NC / 32, NC / 32), 256, 0, stream>>>(w_out, woT, NC, NC);
  k_gemm_bt<1><<<dim3(3 * NC / 128, NB * NT / 128), 256, 0, stream>>>(
      xb, wqT, NB * NT, 3 * NC, NC, Qb, Kb, Vtb, nullptr);
  k_attn<<<dim3(32 * NB * NH), 256, 0, stream>>>(Qb, Kb, Vtb, yb);
  k_gemm_bt<0><<<dim3(NC / 128, NB * NT / 128), 256, 0, stream>>>(
      yb, woT, NB * NT, NC, NC, nullptr, nullptr, nullptr, out);
}